// Round 1
// baseline (3001.641 us; speedup 1.0000x reference)
//
#include <hip/hip_runtime.h>

// Recurrent MLP emulator: B=65536 rows, T=256 steps, MLP 18->32->32->14 with
// residual latent update. One thread per batch row; all state in registers;
// weights read as wave-uniform scalar loads (SGPR broadcast).

#define BB 65536
#define TT 256
#define PP 4
#define LL 14
#define HH 32
#define INW 18

__global__ __launch_bounds__(256, 1)
void emulator_kernel(const float* __restrict__ phys,
                     const float* __restrict__ latents,
                     const float* __restrict__ W1,
                     const float* __restrict__ b1,
                     const float* __restrict__ W2,
                     const float* __restrict__ b2,
                     const float* __restrict__ W3,
                     const float* __restrict__ b3,
                     float* __restrict__ out) {
    const int b = blockIdx.x * blockDim.x + threadIdx.x;

    // Persistent latent state in registers.
    float lat[LL];
#pragma unroll
    for (int l = 0; l < LL; ++l) lat[l] = latents[(size_t)b * LL + l];

    // phys[b][t][0:4] is a 16B-aligned float4.
    const float4* __restrict__ physv =
        reinterpret_cast<const float4*>(phys + (size_t)b * TT * PP);
    float4 ph = physv[0];

    float* __restrict__ outp = out + (size_t)b * TT * LL;

    for (int t = 0; t < TT; ++t) {
        // Prefetch next step's phys (guard the final iteration).
        const int tn = (t < TT - 1) ? (t + 1) : t;
        const float4 ph_next = physv[tn];

        // ---- layer 1: h1 = relu([phys, lat] @ W1 + b1) ----
        float h1[HH];
#pragma unroll
        for (int j = 0; j < HH; ++j) h1[j] = b1[j];
#pragma unroll
        for (int j = 0; j < HH; ++j) {
            h1[j] += ph.x * W1[0 * HH + j];
            h1[j] += ph.y * W1[1 * HH + j];
            h1[j] += ph.z * W1[2 * HH + j];
            h1[j] += ph.w * W1[3 * HH + j];
        }
#pragma unroll
        for (int i = 0; i < LL; ++i) {
            const float xi = lat[i];
#pragma unroll
            for (int j = 0; j < HH; ++j) h1[j] += xi * W1[(PP + i) * HH + j];
        }
#pragma unroll
        for (int j = 0; j < HH; ++j) h1[j] = fmaxf(h1[j], 0.0f);

        // ---- layer 2: h2 = relu(h1 @ W2 + b2) ----
        float h2[HH];
#pragma unroll
        for (int j = 0; j < HH; ++j) h2[j] = b2[j];
#pragma unroll
        for (int k = 0; k < HH; ++k) {
            const float hk = h1[k];
#pragma unroll
            for (int j = 0; j < HH; ++j) h2[j] += hk * W2[k * HH + j];
        }
#pragma unroll
        for (int j = 0; j < HH; ++j) h2[j] = fmaxf(h2[j], 0.0f);

        // ---- layer 3 + residual: lat += h2 @ W3 + b3 ----
#pragma unroll
        for (int l = 0; l < LL; ++l) lat[l] += b3[l];
#pragma unroll
        for (int k = 0; k < HH; ++k) {
            const float hk = h2[k];
#pragma unroll
            for (int l = 0; l < LL; ++l) lat[l] += hk * W3[k * LL + l];
        }

        // ---- store out[b][t][:] : 14 floats, 8B-aligned -> 7 x float2 ----
        float2* __restrict__ o2 = reinterpret_cast<float2*>(outp + t * LL);
#pragma unroll
        for (int l = 0; l < LL / 2; ++l) o2[l] = make_float2(lat[2 * l], lat[2 * l + 1]);

        ph = ph_next;
    }
}

extern "C" void kernel_launch(void* const* d_in, const int* in_sizes, int n_in,
                              void* d_out, int out_size, void* d_ws, size_t ws_size,
                              hipStream_t stream) {
    const float* phys    = (const float*)d_in[0];
    const float* latents = (const float*)d_in[1];
    const float* W1      = (const float*)d_in[2];
    const float* b1      = (const float*)d_in[3];
    const float* W2      = (const float*)d_in[4];
    const float* b2      = (const float*)d_in[5];
    const float* W3      = (const float*)d_in[6];
    const float* b3      = (const float*)d_in[7];
    float* out = (float*)d_out;

    const int threads = 256;
    const int blocks = BB / threads;  // 256 blocks = 1 per CU
    emulator_kernel<<<blocks, threads, 0, stream>>>(
        phys, latents, W1, b1, W2, b2, W3, b3, out);
}